// Round 14
// baseline (213.459 us; speedup 1.0000x reference)
//
#include <hip/hip_runtime.h>

#define NB 32
#define NA 9
#define FH 100
#define FW 100
#define HWSZ (FH*FW)          // 10000
#define NANCH (HWSZ*NA)       // 90000
#define PRE 6000
#define POST 300
#define SORTN 8192
#define NEGV -1000000000.0f
#define NMS_T 0.7f
#define MARG 1e-4f
#define NCHUNK ((PRE + 63) / 64)   // 94
#define WB() __builtin_amdgcn_wave_barrier()
#define NSLICE 11                 // slices per batch: 11*8192 >= 90000
#define DSLICE 8192

typedef unsigned long long u64;
typedef unsigned int u32;

__device__ __forceinline__ u32 f2sort(float f) {
  u32 u = __float_as_uint(f);
  return (u & 0x80000000u) ? ~u : (u | 0x80000000u);
}

// decode from plane-major linear index j: a = j/10000, hw = j%10000
__device__ __forceinline__ float4 decode_box_pm(const float* __restrict__ pred,
                                                const float* __restrict__ anchors,
                                                int b, int a, int hw,
                                                float imw, float imh) {
  int h = hw / FW; int w = hw - h * FW;
  float sx = (float)(w * 16);
  float sy = (float)(h * 16);
  float ax1 = anchors[a*4+0] + sx, ay1 = anchors[a*4+1] + sy;
  float ax2 = anchors[a*4+2] + sx, ay2 = anchors[a*4+3] + sy;
  float wa = ax2 - ax1 + 1.0f, ha = ay2 - ay1 + 1.0f;
  float cxa = ax1 + 0.5f*(wa - 1.0f), cya = ay1 + 0.5f*(ha - 1.0f);
  size_t base = ((size_t)b*36 + a*4)*HWSZ + hw;
  float dx = pred[base];
  float dy = pred[base + HWSZ];
  float dw = pred[base + 2*HWSZ];
  float dh = pred[base + 3*HWSZ];
  float cx = dx*wa + cxa, cy = dy*ha + cya;
  float pw = expf(dw)*wa, ph = expf(dh)*ha;
  float x1 = fminf(fmaxf(cx - 0.5f*(pw - 1.0f), 0.0f), imw - 1.0f);
  float y1 = fminf(fmaxf(cy - 0.5f*(ph - 1.0f), 0.0f), imh - 1.0f);
  float x2 = fminf(fmaxf(cx + 0.5f*(pw - 1.0f), 0.0f), imw - 1.0f);
  float y2 = fminf(fmaxf(cy + 0.5f*(ph - 1.0f), 0.0f), imh - 1.0f);
  return make_float4(x1, y1, x2, y2);
}

// K0: zero histg + binCnt (contiguous 262144 u32)
__global__ void k_zero(u32* __restrict__ histcnt) {
  int i = blockIdx.x * 1024 + threadIdx.x;
  histcnt[i] = 0;      // grid sized exactly 262144
}

// K1: plane-major score + min-size filter -> sortable u32 (coalesced); linear hist
__global__ __launch_bounds__(1024) void k_decode(
    const float* __restrict__ cls,
    const float* __restrict__ pred,
    const float* __restrict__ iminfo,
    const float* __restrict__ anchors,
    u32* __restrict__ scoreg,
    u32* __restrict__ histg) {
  __shared__ u32 hl[4096];
  const int blk = blockIdx.x;
  const int b = blk / NSLICE, s = blk - b * NSLICE;
  const int tid = threadIdx.x;
  for (int j = tid; j < 4096; j += 1024) hl[j] = 0;
  __syncthreads();
  const float imh = iminfo[b*3+0], imw = iminfo[b*3+1], sc = iminfo[b*3+2];
  const float msz = 16.0f * sc;
  #pragma unroll
  for (int r = 0; r < 8; ++r) {
    int j = s * DSLICE + r * 1024 + tid;
    if (j < NANCH) {
      int a = j / HWSZ; int hw = j - a * HWSZ;
      float score = cls[((size_t)b*18 + 9 + a)*HWSZ + hw];
      float4 bx = decode_box_pm(pred, anchors, b, a, hw, imw, imh);
      bool keep = ((bx.z - bx.x + 1.0f) >= msz) && ((bx.w - bx.y + 1.0f) >= msz);
      float sf = keep ? score : NEGV;
      float t = sf * 4096.0f;
      int bin = (t <= 0.0f) ? 0 : ((t >= 4095.0f) ? 4095 : (int)t);
      atomicAdd(&hl[bin], 1u);
      scoreg[(size_t)b * NANCH + j] = f2sort(sf);
    }
  }
  __syncthreads();
  for (int j = tid; j < 4096; j += 1024) {
    u32 v = hl[j];
    if (v) atomicAdd(&histg[b * 4096 + j], v);
  }
}

// wave suffix cut search over 4096-bin histogram (LDS).
__device__ __forceinline__ void w0_cut(u32* hist, u32 target, int lane,
                                       int* cutBin) {
  u32 cs = 0;
  int cb = lane * 64;
  for (int i = 0; i < 64; ++i) cs += hist[cb + ((i + lane) & 63)];
  u32 suf = cs;
  #pragma unroll
  for (int d = 1; d < 64; d <<= 1) {
    u32 o = __shfl_down(suf, (unsigned)d, 64);
    suf += (lane < 64 - d) ? o : 0u;
  }
  u64 m1 = __ballot(suf >= target);
  int L = 63 - __clzll(m1);
  u32 nAb = (L < 63) ? (u32)__builtin_amdgcn_readlane((int)suf, L + 1) : 0u;
  u32 fs = hist[L * 64 + lane];
  #pragma unroll
  for (int d = 1; d < 64; d <<= 1) {
    u32 o = __shfl_down(fs, (unsigned)d, 64);
    fs += (lane < 64 - d) ? o : 0u;
  }
  fs += nAb;
  u64 m2 = __ballot(fs >= target);
  int fb = 63 - __clzll(m2);
  *cutBin = L * 64 + fb;
}

// K2: per-batch (1 wave): cut bin, thrT, descending-suffix binStart, count
__global__ __launch_bounds__(64) void k_cut(const u32* __restrict__ histg,
                                            u32* __restrict__ thrTg,
                                            u32* __restrict__ binStartG,
                                            u32* __restrict__ countG) {
  __shared__ u32 hl[4096];
  const int b = blockIdx.x, lane = threadIdx.x;
  const u32* h = histg + b * 4096;
  for (int i = lane; i < 4096; i += 64) hl[i] = h[i];
  __syncthreads();
  int L;
  w0_cut(hl, PRE, lane, &L);
  u32 running = 0;
  for (int hi = 4095; hi >= L; hi -= 64) {
    int bin = hi - lane;
    u32 c = (bin >= L && bin >= 0) ? hl[bin] : 0u;
    u32 p = c;
    #pragma unroll
    for (int d = 1; d < 64; d <<= 1) {
      u32 o = __shfl_up(p, (unsigned)d, 64);
      if (lane >= d) p += o;
    }
    if (bin >= L && bin >= 0) binStartG[b * 4096 + bin] = running + p - c;
    running += (u32)__builtin_amdgcn_readlane((int)p, 63);
  }
  if (lane == 0) {
    thrTg[b] = f2sort((float)L * (1.0f / 4096.0f));
    countG[b] = running;
  }
}

// K3: scatter qualifying (key, decoded box) into bin segments (full chip)
__global__ __launch_bounds__(1024) void k_scatter(
    const u32* __restrict__ scoreg,
    const u32* __restrict__ thrTg,
    const u32* __restrict__ binStartG,
    u32* __restrict__ binCntG,
    u64* __restrict__ candg,
    float4* __restrict__ boxg,
    const float* __restrict__ pred,
    const float* __restrict__ iminfo,
    const float* __restrict__ anchors) {
  const int blk = blockIdx.x;
  const int b = blk / NSLICE, s = blk - b * NSLICE;
  const int tid = threadIdx.x;
  const u32 thrT = thrTg[b];
  const float imh = iminfo[b*3+0], imw = iminfo[b*3+1];
  const u32* sb = scoreg + (size_t)b * NANCH;
  #pragma unroll
  for (int r = 0; r < 8; ++r) {
    int j = s * DSLICE + r * 1024 + tid;
    if (j < NANCH) {
      u32 sv = sb[j];
      if (sv >= thrT) {
        int a = j / HWSZ; int hw = j - a * HWSZ;
        int i = hw * NA + a;                    // original anchor id (tiebreak)
        float f = __uint_as_float(sv ^ 0x80000000u);   // sv>=thrT>0 -> positive
        float t = f * 4096.0f;
        int bin = (t >= 4095.0f) ? 4095 : (int)t;
        u32 pos = binStartG[b * 4096 + bin] + atomicAdd(&binCntG[b * 4096 + bin], 1u);
        if (pos < SORTN) {
          candg[(size_t)b * SORTN + pos] = ((u64)sv << 32) | (u32)(~(u32)i);
          boxg[(size_t)b * SORTN + pos] = decode_box_pm(pred, anchors, b, a, hw, imw, imh);
        }
      }
    }
  }
}

// K4: one wave per (batch,bin): sort segment descending by key, permute boxes
__global__ __launch_bounds__(512) void k_binsort(
    const u32* __restrict__ binStartG,
    const u32* __restrict__ binCntG,
    u64* __restrict__ candg,
    float4* __restrict__ boxg) {
  __shared__ u64 ks[8][512];
  __shared__ u32 ops[8][512];
  __shared__ float4 bs[8][512];
  const int wave = threadIdx.x >> 6, lane = threadIdx.x & 63;
  const int task = blockIdx.x * 8 + wave;       // 131072 = 32 * 4096
  const int b = task >> 12, bin = task & 4095;
  u32 cnt = binCntG[b * 4096 + bin];
  if (cnt < 2) return;
  u32 base = binStartG[b * 4096 + bin];
  if (base >= SORTN) return;
  u32 m = cnt;
  if (base + m > SORTN) m = SORTN - base;
  u64* seg = candg + (size_t)b * SORTN + base;
  float4* bseg = boxg + (size_t)b * SORTN + base;
  if (m <= 64) {
    u64 v = (lane < (int)m) ? seg[lane] : 0ull;
    u32 op = (u32)lane;
    #pragma unroll
    for (int k = 2; k <= 64; k <<= 1) {
      for (int j = k >> 1; j > 0; j >>= 1) {
        u64 o = __shfl_xor((unsigned long long)v, j, 64);
        u32 oop = __shfl_xor(op, j, 64);
        bool dirD = ((lane & k) == 0);
        bool lower = ((lane & j) == 0);
        bool takeMax = (dirD == lower);
        bool sw = takeMax ? (o > v) : (o < v);
        if (sw) { v = o; op = oop; }
      }
    }
    if (lane < (int)m) seg[lane] = v;
    if (lane < (int)m) {
      float4 bx = bseg[op];                     // op < m for real entries
      bseg[lane] = bx;                          // loads complete before stores
    }
  } else if (m <= 512) {
    int np = 128; while (np < (int)m) np <<= 1;
    for (int i = lane; i < np; i += 64) {
      ks[wave][i] = (i < (int)m) ? seg[i] : 0ull;
      ops[wave][i] = (u32)i;
    }
    WB();
    for (int k = 2; k <= np; k <<= 1) {
      for (int j = k >> 1; j > 0; j >>= 1) {
        for (int q = lane; q < np/2; q += 64) {
          int i = ((q & ~(j-1)) << 1) | (q & (j-1));
          int x = i | j;
          u64 a0 = ks[wave][i], a1 = ks[wave][x];
          bool up = (i & k) != 0;
          if (up ? (a0 > a1) : (a0 < a1)) {
            ks[wave][i] = a1; ks[wave][x] = a0;
            u32 t = ops[wave][i]; ops[wave][i] = ops[wave][x]; ops[wave][x] = t;
          }
        }
        WB();
      }
    }
    for (int i = lane; i < (int)m; i += 64) bs[wave][i] = bseg[ops[wave][i]];
    WB();
    for (int i = lane; i < (int)m; i += 64) {
      seg[i] = ks[wave][i];
      bseg[i] = bs[wave][i];
    }
  }
  // m > 512: statistically impossible (bins avg ~22); same policy as R13
}

// K5: 32 blocks x 512: Phase A coalesced box copy; Phase B 8-wave NMS,
// ONE barrier per chunk (redundant per-wave resolution, dbuf okm)
__global__ __launch_bounds__(512, 1) void k_nms(
    const float4* __restrict__ boxg,
    const u32* __restrict__ countG,
    float* __restrict__ out) {
  __shared__ float4 boxes[NCHUNK * 64];   // 6016
  __shared__ float4 accB[POST];
  __shared__ float accA[POST];
  __shared__ u64 okm[2][8];
  const int b = blockIdx.x;
  const int tid = threadIdx.x;
  const int wave = tid >> 6, lane = tid & 63;
  int cnt = (int)countG[b]; if (cnt > PRE) cnt = PRE;
  const float4* bg = boxg + (size_t)b * SORTN;
  for (int i = tid; i < NCHUNK * 64; i += 512) boxes[i] = bg[i];
  __syncthreads();

  int nAcc = 0, lc = 0;
  for (int g = 0; g < NCHUNK; ++g) {
    if (nAcc >= POST) break;
    int nliv = cnt - g * 64;
    if (nliv <= 0) break;                      // sorted: rest dead
    u64 lm = (nliv >= 64) ? ~0ull : ((1ull << nliv) - 1ull);
    float4 bc = boxes[g * 64 + lane];
    float areaC = (bc.z - bc.x + 1.0f) * (bc.w - bc.y + 1.0f);
    bool ok = (lm >> lane) & 1ull;
    for (int tt = wave; tt < nAcc; tt += 8) {  // independent iters, pipelined
      float4 ba = accB[tt];
      float aA = accA[tt];
      float xx1 = fmaxf(ba.x, bc.x);
      float yy1 = fmaxf(ba.y, bc.y);
      float xx2 = fminf(ba.z, bc.z);
      float yy2 = fminf(ba.w, bc.w);
      float inter = fmaxf(xx2 - xx1 + 1.0f, 0.0f) * fmaxf(yy2 - yy1 + 1.0f, 0.0f);
      float un = aA + areaC - inter;
      float q = inter * __builtin_amdgcn_rcpf(un);
      bool hi = q > NMS_T + MARG;
      bool lo = q < NMS_T - MARG;
      bool sup = hi;
      if (__ballot(ok && !hi && !lo)) {        // rare exact-div fallback
        if (!hi && !lo) sup = (inter / un) > NMS_T;
      }
      ok = ok && !sup;
    }
    u64 wm = __ballot(ok);                     // full-exec ballot
    if (lane == 0) okm[lc & 1][wave] = wm;
    __syncthreads();                           // the ONLY barrier per chunk
    u64 mm = okm[lc & 1][0];
    #pragma unroll
    for (int w = 1; w < 8; ++w) mm &= okm[lc & 1][w];
    ++lc;
    // redundant resolution on EVERY wave (identical results; own-wave LDS
    // writes give next-chunk visibility without a second barrier)
    bool ok0 = (mm >> lane) & 1ull;
    u64 bal = __ballot(ok0);
    while (bal != 0ull && nAcc < POST) {
      int fl = __ffsll(bal) - 1;
      float ax1 = __int_as_float(__builtin_amdgcn_readlane(__float_as_int(bc.x), fl));
      float ay1 = __int_as_float(__builtin_amdgcn_readlane(__float_as_int(bc.y), fl));
      float ax2 = __int_as_float(__builtin_amdgcn_readlane(__float_as_int(bc.z), fl));
      float ay2 = __int_as_float(__builtin_amdgcn_readlane(__float_as_int(bc.w), fl));
      float aA = (ax2 - ax1 + 1.0f) * (ay2 - ay1 + 1.0f);
      if (lane == 0) { accB[nAcc] = make_float4(ax1, ay1, ax2, ay2); accA[nAcc] = aA; }
      ++nAcc;
      if (ok0) {
        if (lane == fl) ok0 = false;
        else if (lane > fl) {
          float xx1 = fmaxf(ax1, bc.x);
          float yy1 = fmaxf(ay1, bc.y);
          float xx2 = fminf(ax2, bc.z);
          float yy2 = fminf(ay2, bc.w);
          float inter = fmaxf(xx2 - xx1 + 1.0f, 0.0f) * fmaxf(yy2 - yy1 + 1.0f, 0.0f);
          float iou = inter / (aA + areaC - inter);
          if (iou > NMS_T) ok0 = false;
        }
      }
      bal = __ballot(ok0);
    }
  }

  // ---- output: [b][POST][5] = (b, x1, y1, x2, y2); rows >= nAcc zeroed ----
  float* ob = out + (size_t)b * POST * 5;
  for (int i = tid; i < POST * 5; i += 512) {
    int row = i / 5, col = i - row * 5;
    float v = 0.f;
    if (col == 0) v = (float)b;
    else if (row < nAcc) {
      float4 bb = accB[row];
      v = (col == 1) ? bb.x : (col == 2) ? bb.y : (col == 3) ? bb.z : bb.w;
    }
    ob[i] = v;
  }
}

extern "C" void kernel_launch(void* const* d_in, const int* in_sizes, int n_in,
                              void* d_out, int out_size, void* d_ws, size_t ws_size,
                              hipStream_t stream) {
  const float* cls     = (const float*)d_in[0];
  const float* pred    = (const float*)d_in[1];
  const float* iminfo  = (const float*)d_in[2];
  const float* anchors = (const float*)d_in[3];
  float* out = (float*)d_out;

  char* ws = (char*)d_ws;
  u32* histg     = (u32*)(ws + 0);            // 512 KB
  u32* binCntG   = (u32*)(ws + 524288);       // 512 KB (contiguous after histg)
  u32* binStartG = (u32*)(ws + 1048576);      // 512 KB
  u32* thrTg     = (u32*)(ws + 1572864);      // 128 B
  u32* countG    = (u32*)(ws + 1572992);      // 128 B
  u64* candg     = (u64*)(ws + 1573120);      // 2 MB   (32*8192*8)
  float4* boxg   = (float4*)(ws + 3670272);   // 4 MB   (32*8192*16)
  u32* scoreg    = (u32*)(ws + 7864576);      // 11.52 MB

  k_zero<<<256, 1024, 0, stream>>>(histg);    // zeroes histg+binCnt (1 MB)
  k_decode<<<NB*NSLICE, 1024, 0, stream>>>(cls, pred, iminfo, anchors, scoreg, histg);
  k_cut<<<NB, 64, 0, stream>>>(histg, thrTg, binStartG, countG);
  k_scatter<<<NB*NSLICE, 1024, 0, stream>>>(scoreg, thrTg, binStartG, binCntG,
                                            candg, boxg, pred, iminfo, anchors);
  k_binsort<<<16384, 512, 0, stream>>>(binStartG, binCntG, candg, boxg);
  k_nms<<<NB, 512, 0, stream>>>(boxg, countG, out);
}

// Round 15
// 205.794 us; speedup vs baseline: 1.0372x; 1.0372x over previous
//
#include <hip/hip_runtime.h>

#define NB 32
#define NA 9
#define FH 100
#define FW 100
#define HWSZ (FH*FW)          // 10000
#define NANCH (HWSZ*NA)       // 90000
#define PRE 6000
#define POST 300
#define SORTN 8192
#define NEGV -1000000000.0f
#define NMS_T 0.7f
#define MARG 1e-4f
#define NCHUNK ((PRE + 63) / 64)   // 94
#define WB() __builtin_amdgcn_wave_barrier()
#define NSLICE 11                 // slices per batch: 11*8192 >= 90000
#define DSLICE 8192

typedef unsigned long long u64;
typedef unsigned int u32;

__device__ __forceinline__ u32 f2sort(float f) {
  u32 u = __float_as_uint(f);
  return (u & 0x80000000u) ? ~u : (u | 0x80000000u);
}

// decode from plane-major linear index j: a = j/10000, hw = j%10000
__device__ __forceinline__ float4 decode_box_pm(const float* __restrict__ pred,
                                                const float* __restrict__ anchors,
                                                int b, int a, int hw,
                                                float imw, float imh) {
  int h = hw / FW; int w = hw - h * FW;
  float sx = (float)(w * 16);
  float sy = (float)(h * 16);
  float ax1 = anchors[a*4+0] + sx, ay1 = anchors[a*4+1] + sy;
  float ax2 = anchors[a*4+2] + sx, ay2 = anchors[a*4+3] + sy;
  float wa = ax2 - ax1 + 1.0f, ha = ay2 - ay1 + 1.0f;
  float cxa = ax1 + 0.5f*(wa - 1.0f), cya = ay1 + 0.5f*(ha - 1.0f);
  size_t base = ((size_t)b*36 + a*4)*HWSZ + hw;
  float dx = pred[base];
  float dy = pred[base + HWSZ];
  float dw = pred[base + 2*HWSZ];
  float dh = pred[base + 3*HWSZ];
  float cx = dx*wa + cxa, cy = dy*ha + cya;
  float pw = expf(dw)*wa, ph = expf(dh)*ha;
  float x1 = fminf(fmaxf(cx - 0.5f*(pw - 1.0f), 0.0f), imw - 1.0f);
  float y1 = fminf(fmaxf(cy - 0.5f*(ph - 1.0f), 0.0f), imh - 1.0f);
  float x2 = fminf(fmaxf(cx + 0.5f*(pw - 1.0f), 0.0f), imw - 1.0f);
  float y2 = fminf(fmaxf(cy + 0.5f*(ph - 1.0f), 0.0f), imh - 1.0f);
  return make_float4(x1, y1, x2, y2);
}

// K0: zero histg + binCnt (contiguous 262144 u32)
__global__ void k_zero(u32* __restrict__ histcnt) {
  int i = blockIdx.x * 1024 + threadIdx.x;
  histcnt[i] = 0;      // grid sized exactly 262144
}

// K1: plane-major score + min-size filter -> sortable u32 (coalesced); linear hist
__global__ __launch_bounds__(1024) void k_decode(
    const float* __restrict__ cls,
    const float* __restrict__ pred,
    const float* __restrict__ iminfo,
    const float* __restrict__ anchors,
    u32* __restrict__ scoreg,
    u32* __restrict__ histg) {
  __shared__ u32 hl[4096];
  const int blk = blockIdx.x;
  const int b = blk / NSLICE, s = blk - b * NSLICE;
  const int tid = threadIdx.x;
  for (int j = tid; j < 4096; j += 1024) hl[j] = 0;
  __syncthreads();
  const float imh = iminfo[b*3+0], imw = iminfo[b*3+1], sc = iminfo[b*3+2];
  const float msz = 16.0f * sc;
  #pragma unroll
  for (int r = 0; r < 8; ++r) {
    int j = s * DSLICE + r * 1024 + tid;
    if (j < NANCH) {
      int a = j / HWSZ; int hw = j - a * HWSZ;
      float score = cls[((size_t)b*18 + 9 + a)*HWSZ + hw];
      float4 bx = decode_box_pm(pred, anchors, b, a, hw, imw, imh);
      bool keep = ((bx.z - bx.x + 1.0f) >= msz) && ((bx.w - bx.y + 1.0f) >= msz);
      float sf = keep ? score : NEGV;
      float t = sf * 4096.0f;
      int bin = (t <= 0.0f) ? 0 : ((t >= 4095.0f) ? 4095 : (int)t);
      atomicAdd(&hl[bin], 1u);
      scoreg[(size_t)b * NANCH + j] = f2sort(sf);
    }
  }
  __syncthreads();
  for (int j = tid; j < 4096; j += 1024) {
    u32 v = hl[j];
    if (v) atomicAdd(&histg[b * 4096 + j], v);
  }
}

// wave suffix cut search over 4096-bin histogram (LDS).
__device__ __forceinline__ void w0_cut(u32* hist, u32 target, int lane,
                                       int* cutBin) {
  u32 cs = 0;
  int cb = lane * 64;
  for (int i = 0; i < 64; ++i) cs += hist[cb + ((i + lane) & 63)];
  u32 suf = cs;
  #pragma unroll
  for (int d = 1; d < 64; d <<= 1) {
    u32 o = __shfl_down(suf, (unsigned)d, 64);
    suf += (lane < 64 - d) ? o : 0u;
  }
  u64 m1 = __ballot(suf >= target);
  int L = 63 - __clzll(m1);
  u32 nAb = (L < 63) ? (u32)__builtin_amdgcn_readlane((int)suf, L + 1) : 0u;
  u32 fs = hist[L * 64 + lane];
  #pragma unroll
  for (int d = 1; d < 64; d <<= 1) {
    u32 o = __shfl_down(fs, (unsigned)d, 64);
    fs += (lane < 64 - d) ? o : 0u;
  }
  fs += nAb;
  u64 m2 = __ballot(fs >= target);
  int fb = 63 - __clzll(m2);
  *cutBin = L * 64 + fb;
}

// K2: per-batch (1 wave): cut bin, thrT, descending-suffix binStart, count
__global__ __launch_bounds__(64) void k_cut(const u32* __restrict__ histg,
                                            u32* __restrict__ thrTg,
                                            u32* __restrict__ binStartG,
                                            u32* __restrict__ countG) {
  __shared__ u32 hl[4096];
  const int b = blockIdx.x, lane = threadIdx.x;
  const u32* h = histg + b * 4096;
  for (int i = lane; i < 4096; i += 64) hl[i] = h[i];
  __syncthreads();
  int L;
  w0_cut(hl, PRE, lane, &L);
  u32 running = 0;
  for (int hi = 4095; hi >= L; hi -= 64) {
    int bin = hi - lane;
    u32 c = (bin >= L && bin >= 0) ? hl[bin] : 0u;
    u32 p = c;
    #pragma unroll
    for (int d = 1; d < 64; d <<= 1) {
      u32 o = __shfl_up(p, (unsigned)d, 64);
      if (lane >= d) p += o;
    }
    if (bin >= L && bin >= 0) binStartG[b * 4096 + bin] = running + p - c;
    running += (u32)__builtin_amdgcn_readlane((int)p, 63);
  }
  if (lane == 0) {
    thrTg[b] = f2sort((float)L * (1.0f / 4096.0f));
    countG[b] = running;
  }
}

// K3: scatter qualifying (key, decoded box) into bin segments (full chip)
__global__ __launch_bounds__(1024) void k_scatter(
    const u32* __restrict__ scoreg,
    const u32* __restrict__ thrTg,
    const u32* __restrict__ binStartG,
    u32* __restrict__ binCntG,
    u64* __restrict__ candg,
    float4* __restrict__ boxg,
    const float* __restrict__ pred,
    const float* __restrict__ iminfo,
    const float* __restrict__ anchors) {
  const int blk = blockIdx.x;
  const int b = blk / NSLICE, s = blk - b * NSLICE;
  const int tid = threadIdx.x;
  const u32 thrT = thrTg[b];
  const float imh = iminfo[b*3+0], imw = iminfo[b*3+1];
  const u32* sb = scoreg + (size_t)b * NANCH;
  #pragma unroll
  for (int r = 0; r < 8; ++r) {
    int j = s * DSLICE + r * 1024 + tid;
    if (j < NANCH) {
      u32 sv = sb[j];
      if (sv >= thrT) {
        int a = j / HWSZ; int hw = j - a * HWSZ;
        int i = hw * NA + a;                    // original anchor id (tiebreak)
        float f = __uint_as_float(sv ^ 0x80000000u);   // sv>=thrT>0 -> positive
        float t = f * 4096.0f;
        int bin = (t >= 4095.0f) ? 4095 : (int)t;
        u32 pos = binStartG[b * 4096 + bin] + atomicAdd(&binCntG[b * 4096 + bin], 1u);
        if (pos < SORTN) {
          candg[(size_t)b * SORTN + pos] = ((u64)sv << 32) | (u32)(~(u32)i);
          boxg[(size_t)b * SORTN + pos] = decode_box_pm(pred, anchors, b, a, hw, imw, imh);
        }
      }
    }
  }
}

// K4: one wave per (batch,bin): sort segment descending by key, permute boxes
__global__ __launch_bounds__(512) void k_binsort(
    const u32* __restrict__ binStartG,
    const u32* __restrict__ binCntG,
    u64* __restrict__ candg,
    float4* __restrict__ boxg) {
  __shared__ u64 ks[8][512];
  __shared__ u32 ops[8][512];
  __shared__ float4 bs[8][512];
  const int wave = threadIdx.x >> 6, lane = threadIdx.x & 63;
  const int task = blockIdx.x * 8 + wave;       // 131072 = 32 * 4096
  const int b = task >> 12, bin = task & 4095;
  u32 cnt = binCntG[b * 4096 + bin];
  if (cnt < 2) return;
  u32 base = binStartG[b * 4096 + bin];
  if (base >= SORTN) return;
  u32 m = cnt;
  if (base + m > SORTN) m = SORTN - base;
  u64* seg = candg + (size_t)b * SORTN + base;
  float4* bseg = boxg + (size_t)b * SORTN + base;
  if (m <= 64) {
    u64 v = (lane < (int)m) ? seg[lane] : 0ull;
    u32 op = (u32)lane;
    #pragma unroll
    for (int k = 2; k <= 64; k <<= 1) {
      for (int j = k >> 1; j > 0; j >>= 1) {
        u64 o = __shfl_xor((unsigned long long)v, j, 64);
        u32 oop = __shfl_xor(op, j, 64);
        bool dirD = ((lane & k) == 0);
        bool lower = ((lane & j) == 0);
        bool takeMax = (dirD == lower);
        bool sw = takeMax ? (o > v) : (o < v);
        if (sw) { v = o; op = oop; }
      }
    }
    if (lane < (int)m) seg[lane] = v;
    if (lane < (int)m) {
      float4 bx = bseg[op];                     // op < m for real entries
      bseg[lane] = bx;                          // loads complete before stores
    }
  } else if (m <= 512) {
    int np = 128; while (np < (int)m) np <<= 1;
    for (int i = lane; i < np; i += 64) {
      ks[wave][i] = (i < (int)m) ? seg[i] : 0ull;
      ops[wave][i] = (u32)i;
    }
    WB();
    for (int k = 2; k <= np; k <<= 1) {
      for (int j = k >> 1; j > 0; j >>= 1) {
        for (int q = lane; q < np/2; q += 64) {
          int i = ((q & ~(j-1)) << 1) | (q & (j-1));
          int x = i | j;
          u64 a0 = ks[wave][i], a1 = ks[wave][x];
          bool up = (i & k) != 0;
          if (up ? (a0 > a1) : (a0 < a1)) {
            ks[wave][i] = a1; ks[wave][x] = a0;
            u32 t = ops[wave][i]; ops[wave][i] = ops[wave][x]; ops[wave][x] = t;
          }
        }
        WB();
      }
    }
    for (int i = lane; i < (int)m; i += 64) bs[wave][i] = bseg[ops[wave][i]];
    WB();
    for (int i = lane; i < (int)m; i += 64) {
      seg[i] = ks[wave][i];
      bseg[i] = bs[wave][i];
    }
  }
  // m > 512: statistically impossible (bins avg ~22)
}

// K5: 32 blocks x 512: Phase A coalesced box copy; Phase B 8-wave NMS,
// ONE barrier per chunk; test loop has NO wave-wide ops (pipelines fully)
__global__ __launch_bounds__(512, 1) void k_nms(
    const float4* __restrict__ boxg,
    const u32* __restrict__ countG,
    float* __restrict__ out) {
  __shared__ float4 boxes[NCHUNK * 64];   // 6016
  __shared__ float4 accB[POST];
  __shared__ float accA[POST];
  __shared__ u64 okm[2][8];
  const int b = blockIdx.x;
  const int tid = threadIdx.x;
  const int wave = tid >> 6, lane = tid & 63;
  int cnt = (int)countG[b]; if (cnt > PRE) cnt = PRE;
  const float4* bg = boxg + (size_t)b * SORTN;
  for (int i = tid; i < NCHUNK * 64; i += 512) boxes[i] = bg[i];
  __syncthreads();

  int nAcc = 0, lc = 0;
  for (int g = 0; g < NCHUNK; ++g) {
    if (nAcc >= POST) break;
    int nliv = cnt - g * 64;
    if (nliv <= 0) break;                      // sorted: rest dead
    u64 lm = (nliv >= 64) ? ~0ull : ((1ull << nliv) - 1ull);
    float4 bc = boxes[g * 64 + lane];
    float areaC = (bc.z - bc.x + 1.0f) * (bc.w - bc.y + 1.0f);
    bool ok = (lm >> lane) & 1ull;
    // ---- accepted-list test: independent iterations, no wave-wide ops ----
    #pragma unroll 2
    for (int tt = wave; tt < nAcc; tt += 8) {
      float4 ba = accB[tt];
      float aA = accA[tt];
      float xx1 = fmaxf(ba.x, bc.x);
      float yy1 = fmaxf(ba.y, bc.y);
      float xx2 = fminf(ba.z, bc.z);
      float yy2 = fminf(ba.w, bc.w);
      float inter = fmaxf(xx2 - xx1 + 1.0f, 0.0f) * fmaxf(yy2 - yy1 + 1.0f, 0.0f);
      float un = aA + areaC - inter;
      float q = inter * __builtin_amdgcn_rcpf(un);
      bool sup = q > NMS_T + MARG;
      if (!sup && q > NMS_T - MARG)            // rare per-lane exact fallback
        sup = (inter / un) > NMS_T;
      ok = ok && !sup;
    }
    u64 wm = __ballot(ok);                     // full-exec ballot
    if (lane == 0) okm[lc & 1][wave] = wm;
    __syncthreads();                           // the ONLY barrier per chunk
    u64 mm = okm[lc & 1][0];
    #pragma unroll
    for (int w = 1; w < 8; ++w) mm &= okm[lc & 1][w];
    ++lc;
    // redundant resolution on EVERY wave (identical results; own-wave LDS
    // writes give next-chunk visibility without a second barrier)
    bool ok0 = (mm >> lane) & 1ull;
    u64 bal = __ballot(ok0);
    while (bal != 0ull && nAcc < POST) {
      int fl = __ffsll(bal) - 1;
      float ax1 = __int_as_float(__builtin_amdgcn_readlane(__float_as_int(bc.x), fl));
      float ay1 = __int_as_float(__builtin_amdgcn_readlane(__float_as_int(bc.y), fl));
      float ax2 = __int_as_float(__builtin_amdgcn_readlane(__float_as_int(bc.z), fl));
      float ay2 = __int_as_float(__builtin_amdgcn_readlane(__float_as_int(bc.w), fl));
      float aA = (ax2 - ax1 + 1.0f) * (ay2 - ay1 + 1.0f);
      if (lane == 0) { accB[nAcc] = make_float4(ax1, ay1, ax2, ay2); accA[nAcc] = aA; }
      ++nAcc;
      if (ok0) {
        if (lane == fl) ok0 = false;
        else if (lane > fl) {
          float xx1 = fmaxf(ax1, bc.x);
          float yy1 = fmaxf(ay1, bc.y);
          float xx2 = fminf(ax2, bc.z);
          float yy2 = fminf(ay2, bc.w);
          float inter = fmaxf(xx2 - xx1 + 1.0f, 0.0f) * fmaxf(yy2 - yy1 + 1.0f, 0.0f);
          float iou = inter / (aA + areaC - inter);
          if (iou > NMS_T) ok0 = false;
        }
      }
      bal = __ballot(ok0);
    }
  }

  // ---- output: [b][POST][5] = (b, x1, y1, x2, y2); rows >= nAcc zeroed ----
  float* ob = out + (size_t)b * POST * 5;
  for (int i = tid; i < POST * 5; i += 512) {
    int row = i / 5, col = i - row * 5;
    float v = 0.f;
    if (col == 0) v = (float)b;
    else if (row < nAcc) {
      float4 bb = accB[row];
      v = (col == 1) ? bb.x : (col == 2) ? bb.y : (col == 3) ? bb.z : bb.w;
    }
    ob[i] = v;
  }
}

extern "C" void kernel_launch(void* const* d_in, const int* in_sizes, int n_in,
                              void* d_out, int out_size, void* d_ws, size_t ws_size,
                              hipStream_t stream) {
  const float* cls     = (const float*)d_in[0];
  const float* pred    = (const float*)d_in[1];
  const float* iminfo  = (const float*)d_in[2];
  const float* anchors = (const float*)d_in[3];
  float* out = (float*)d_out;

  char* ws = (char*)d_ws;
  u32* histg     = (u32*)(ws + 0);            // 512 KB
  u32* binCntG   = (u32*)(ws + 524288);       // 512 KB (contiguous after histg)
  u32* binStartG = (u32*)(ws + 1048576);      // 512 KB
  u32* thrTg     = (u32*)(ws + 1572864);      // 128 B
  u32* countG    = (u32*)(ws + 1572992);      // 128 B
  u64* candg     = (u64*)(ws + 1573120);      // 2 MB   (32*8192*8)
  float4* boxg   = (float4*)(ws + 3670272);   // 4 MB   (32*8192*16)
  u32* scoreg    = (u32*)(ws + 7864576);      // 11.52 MB

  k_zero<<<256, 1024, 0, stream>>>(histg);    // zeroes histg+binCnt (1 MB)
  k_decode<<<NB*NSLICE, 1024, 0, stream>>>(cls, pred, iminfo, anchors, scoreg, histg);
  k_cut<<<NB, 64, 0, stream>>>(histg, thrTg, binStartG, countG);
  k_scatter<<<NB*NSLICE, 1024, 0, stream>>>(scoreg, thrTg, binStartG, binCntG,
                                            candg, boxg, pred, iminfo, anchors);
  k_binsort<<<16384, 512, 0, stream>>>(binStartG, binCntG, candg, boxg);
  k_nms<<<NB, 512, 0, stream>>>(boxg, countG, out);
}